// Round 14
// baseline (160.942 us; speedup 1.0000x reference)
//
#include <hip/hip_runtime.h>
#include <math.h>

#define NQ 12
#define DIM 4096
#define BATCH 2048

// Native clang vector types: __builtin_nontemporal_* requires true vectors of
// scalars, not HIP's HIP_vector_type classes.
typedef float fv4 __attribute__((ext_vector_type(4)));
typedef float fv2 __attribute__((ext_vector_type(2)));

#if defined(__has_builtin)
#if __has_builtin(__builtin_nontemporal_load) && __has_builtin(__builtin_nontemporal_store)
#define NT_LOAD(p)     __builtin_nontemporal_load(p)
#define NT_STORE(p, v) __builtin_nontemporal_store((v), (p))
#endif
#endif
#ifndef NT_LOAD
#define NT_LOAD(p)     (*(p))
#define NT_STORE(p, v) (*(p) = (v))
#endif

// XOR swizzle on float2 index: both swap patterns below land at the b64
// minimum lanes-per-bank. Bijective on [0,4096).
__device__ __forceinline__ int swz(int e) { return e ^ ((e >> 4) & 15); }

__device__ __forceinline__ float2 cmulf(float2 a, float2 b) {
    return make_float2(a.x * b.x - a.y * b.y, a.x * b.y + a.y * b.x);
}

// General 2x2 stage over local bit m (row-vector convention):
//   (u', w') = (u*m00 + w*m10, u*m01 + w*m11)
__device__ __forceinline__ void gstage(float (&vr)[16], float (&vi)[16],
                                       float2 m00, float2 m01,
                                       float2 m10, float2 m11, int m) {
#pragma unroll
    for (int r = 0; r < 16; ++r) {
        if (r & m) continue;
        const int p = r | m;
        const float ur = vr[r], ui = vi[r], wr = vr[p], wi = vi[p];
        vr[r] = ur * m00.x - ui * m00.y + wr * m10.x - wi * m10.y;
        vi[r] = ur * m00.y + ui * m00.x + wr * m10.y + wi * m10.x;
        vr[p] = ur * m01.x - ui * m01.y + wr * m11.x - wi * m11.y;
        vi[p] = ur * m01.y + ui * m01.x + wr * m11.y + wi * m11.x;
    }
}

// Apply the 4 per-qubit matrices for local bits 1,2,4,8 (qubit ids q1,q2,q4,q8).
__device__ __forceinline__ void gbf4(float (&vr)[16], float (&vi)[16],
                                     const float2 (*mt)[4],
                                     int q1, int q2, int q4, int q8) {
    gstage(vr, vi, mt[q1][0], mt[q1][1], mt[q1][2], mt[q1][3], 1);
    gstage(vr, vi, mt[q2][0], mt[q2][1], mt[q2][2], mt[q2][3], 2);
    gstage(vr, vi, mt[q4][0], mt[q4][1], mt[q4][2], mt[q4][3], 4);
    gstage(vr, vi, mt[q8][0], mt[q8][1], mt[q8][2], mt[q8][3], 8);
}

// Whole op per qubit k collapses to ONE 2x2 (row-vector x @ M):
//   M = D_in * B * D_th * B * D_ph,  a = e^{i theta}:
//   M00 = e^{i(alpha+phi)} (a-1)/2        M01 = e^{i alpha} i(a+1)/2
//   M10 = e^{i(beta+phi)}  i(a+1)/2       M11 = e^{i beta}  (1-a)/2
// (exact normalization included). 12 general stages replace 24 butterflies +
// 3 diagonal passes -> 2 LDS swaps / 5 barriers per row instead of 4 / 9.
// R13 PMC: qlayer 40.9us, HBM 41%, VALU 35% -> serialization-bound; this
// halves the LDS/barrier critical path.
//
// Layouts (elem bits; t = thread 0..255, r = local 0..15; qubit k <-> bit 11-k):
//  A: elem = r[3:2]<<10 | t<<2 | r[1:0]   local bits {0,1,10,11} = q {11,10,1,0}
//  B: elem = t[7:2]<<6  | r<<2 | t[1:0]   local bits {2,3,4,5}   = q {9,8,7,6}
//  C: elem = t[7:6]<<10 | r<<6 | t[5:0]   local bits {6,7,8,9}   = q {5,4,3,2}
template <bool INTERLEAVED>
__global__ __launch_bounds__(256, 4) void qlayer(
        const float* __restrict__ xr, const float* __restrict__ xi,
        const float* __restrict__ alphas, const float* __restrict__ betas,
        const float* __restrict__ thetas, const float* __restrict__ phis,
        float* __restrict__ out) {
    __shared__ float2 lds[DIM];
    __shared__ float2 mt[NQ][4];

    const int t = threadIdx.x;
    const int row = blockIdx.x;

    // ---- issue x loads immediately (layout A, fv4, non-temporal) ----
    fv4 lre[4], lim[4];
    {
        const float* xrp = xr + (size_t)row * DIM;
        const float* xip = xi + (size_t)row * DIM;
#pragma unroll
        for (int c = 0; c < 4; ++c) {
            const int e0 = (c << 10) + (t << 2);
            lre[c] = NT_LOAD(reinterpret_cast<const fv4*>(xrp + e0));
            lim[c] = NT_LOAD(reinterpret_cast<const fv4*>(xip + e0));
        }
    }

    // ---- 12 per-qubit 2x2 matrices (overlaps with x loads) ----
    if (t < NQ) {
        float sa, ca;
        sincosf(thetas[t], &sa, &ca);
        const float2 h0 = make_float2((ca - 1.f) * 0.5f, sa * 0.5f);   // (a-1)/2
        const float2 h1 = make_float2(-sa * 0.5f, (ca + 1.f) * 0.5f);  // i(a+1)/2
        const float al = alphas[t], be = betas[t], ph = phis[t];
        float s, c;
        sincosf(al + ph, &s, &c); mt[t][0] = cmulf(make_float2(c, s), h0);
        sincosf(al, &s, &c);      mt[t][1] = cmulf(make_float2(c, s), h1);
        sincosf(be + ph, &s, &c); mt[t][2] = cmulf(make_float2(c, s), h1);
        sincosf(be, &s, &c);      mt[t][3] = cmulf(make_float2(c, s),
                                                   make_float2(-h0.x, -h0.y));
    }
    __syncthreads();

    float vr[16], vi[16];
#pragma unroll
    for (int c = 0; c < 4; ++c)
#pragma unroll
        for (int j = 0; j < 4; ++j) {
            vr[c * 4 + j] = lre[c][j];
            vi[c * 4 + j] = lim[c][j];
        }

    gbf4(vr, vi, mt, 11, 10, 1, 0);    // layout A qubits

    // ---- swap A -> B ----
#pragma unroll
    for (int r = 0; r < 16; ++r) {
        const int e = ((r >> 2) << 10) | (t << 2) | (r & 3);
        lds[swz(e)] = make_float2(vr[r], vi[r]);
    }
    __syncthreads();
#pragma unroll
    for (int r = 0; r < 16; ++r) {
        const int e = ((t >> 2) << 6) | (r << 2) | (t & 3);
        float2 v = lds[swz(e)];
        vr[r] = v.x; vi[r] = v.y;
    }
    __syncthreads();

    gbf4(vr, vi, mt, 9, 8, 7, 6);      // layout B qubits

    // ---- swap B -> C ----
#pragma unroll
    for (int r = 0; r < 16; ++r) {
        const int e = ((t >> 2) << 6) | (r << 2) | (t & 3);
        lds[swz(e)] = make_float2(vr[r], vi[r]);
    }
    __syncthreads();
#pragma unroll
    for (int r = 0; r < 16; ++r) {
        const int e = ((t >> 6) << 10) | (r << 6) | (t & 63);
        float2 v = lds[swz(e)];
        vr[r] = v.x; vi[r] = v.y;
    }
    // no more LDS writes -> no trailing barrier

    gbf4(vr, vi, mt, 5, 4, 3, 2);      // layout C qubits — all 12 done

    // ---- store (layout C; per-wave contiguous 256B/512B runs) ----
    if (INTERLEAVED) {
        float2* outp = reinterpret_cast<float2*>(out) + (size_t)row * DIM;
#pragma unroll
        for (int r = 0; r < 16; ++r) {
            const int e = ((t >> 6) << 10) | (r << 6) | (t & 63);
            fv2 o; o.x = vr[r]; o.y = vi[r];
            NT_STORE(reinterpret_cast<fv2*>(outp + e), o);
        }
    } else {
        // Real part only: out is [BATCH][DIM] float32.
        float* outp = out + (size_t)row * DIM;
#pragma unroll
        for (int r = 0; r < 16; ++r) {
            const int e = ((t >> 6) << 10) | (r << 6) | (t & 63);
            NT_STORE(outp + e, vr[r]);
        }
    }
}

extern "C" void kernel_launch(void* const* d_in, const int* in_sizes, int n_in,
                              void* d_out, int out_size, void* d_ws, size_t ws_size,
                              hipStream_t stream) {
    const float* xr     = (const float*)d_in[0];
    const float* xi     = (const float*)d_in[1];
    const float* alphas = (const float*)d_in[2];
    const float* betas  = (const float*)d_in[3];
    const float* thetas = (const float*)d_in[4];
    const float* phis   = (const float*)d_in[5];

    // out_size-adaptive store: complex64 interleaved needs 2*BATCH*DIM floats;
    // the observed harness reference is BATCH*DIM float32 (real part).
    if (out_size >= 2 * BATCH * DIM) {
        qlayer<true><<<BATCH, 256, 0, stream>>>(xr, xi, alphas, betas, thetas,
                                                phis, (float*)d_out);
    } else {
        qlayer<false><<<BATCH, 256, 0, stream>>>(xr, xi, alphas, betas, thetas,
                                                 phis, (float*)d_out);
    }
}

// Round 15
// 127.866 us; speedup vs baseline: 1.2587x; 1.2587x over previous
//
#include <hip/hip_runtime.h>
#include <math.h>

#define NQ 12
#define DIM 4096
#define BATCH 2048

// Native clang vector types: __builtin_nontemporal_* requires true vectors of
// scalars, not HIP's HIP_vector_type classes.
typedef float fv4 __attribute__((ext_vector_type(4)));
typedef float fv2 __attribute__((ext_vector_type(2)));

#if defined(__has_builtin)
#if __has_builtin(__builtin_nontemporal_load) && __has_builtin(__builtin_nontemporal_store)
#define NT_LOAD(p)     __builtin_nontemporal_load(p)
#define NT_STORE(p, v) __builtin_nontemporal_store((v), (p))
#endif
#endif
#ifndef NT_LOAD
#define NT_LOAD(p)     (*(p))
#define NT_STORE(p, v) (*(p) = (v))
#endif

__device__ __forceinline__ float2 cmulf(float2 a, float2 b) {
    return make_float2(a.x * b.x - a.y * b.y, a.x * b.y + a.y * b.x);
}

// General 2x2 stage over thread-local bit m (row-vector convention):
//   (u', w') = (u*m00 + w*m10, u*m01 + w*m11)
// Explicit fmaf chains: exactly 1 mul + 3 fma per component (R14 post-mortem:
// VALU cycles ~2x the ideal count -> force contraction).
__device__ __forceinline__ void gstage(float (&vr)[16], float (&vi)[16],
                                       float2 m00, float2 m01,
                                       float2 m10, float2 m11, int m) {
#pragma unroll
    for (int r = 0; r < 16; ++r) {
        if (r & m) continue;
        const int p = r | m;
        const float ur = vr[r], ui = vi[r], wr = vr[p], wi = vi[p];
        vr[r] = fmaf(ur, m00.x, fmaf(-ui, m00.y, fmaf(wr, m10.x, -wi * m10.y)));
        vi[r] = fmaf(ur, m00.y, fmaf( ui, m00.x, fmaf(wr, m10.y,  wi * m10.x)));
        vr[p] = fmaf(ur, m01.x, fmaf(-ui, m01.y, fmaf(wr, m11.x, -wi * m11.y)));
        vi[p] = fmaf(ur, m01.y, fmaf( ui, m01.x, fmaf(wr, m11.y,  wi * m11.x)));
    }
}

// Apply the merged per-qubit 2x2 for the 4 thread-local bits. Matrices are
// copied to explicit locals FIRST (one clustered burst of 16 broadcast b64
// reads per phase, instead of R14's 48 interleaved reads with waits).
__device__ __forceinline__ void apply4(float (&vr)[16], float (&vi)[16],
                                       const float2 (*mt)[4],
                                       int q1, int q2, int q4, int q8) {
    float2 a0 = mt[q1][0], a1 = mt[q1][1], a2 = mt[q1][2], a3 = mt[q1][3];
    float2 b0 = mt[q2][0], b1 = mt[q2][1], b2 = mt[q2][2], b3 = mt[q2][3];
    float2 c0 = mt[q4][0], c1 = mt[q4][1], c2 = mt[q4][2], c3 = mt[q4][3];
    float2 d0 = mt[q8][0], d1 = mt[q8][1], d2 = mt[q8][2], d3 = mt[q8][3];
    gstage(vr, vi, a0, a1, a2, a3, 1);
    gstage(vr, vi, b0, b1, b2, b3, 2);
    gstage(vr, vi, c0, c1, c2, c3, 4);
    gstage(vr, vi, d0, d1, d2, d3, 8);
}

// Whole op per qubit k is ONE 2x2 (row-vector x @ M), HW-verified in R14:
//   a = e^{i theta}:
//   M00 = e^{i(alpha+phi)} (a-1)/2        M01 = e^{i alpha} i(a+1)/2
//   M10 = e^{i(beta+phi)}  i(a+1)/2       M11 = e^{i beta}  (1-a)/2
//
// Layouts (t = w<<6|l, w = t[7:6], l = t[5:0]; qubit k <-> elem bit 11-k):
//  A: elem = w<<10 | l<<4 | r     r = elem[3:0]  -> qubits {11,10,9,8}
//  B: elem = w<<10 | l[5:4]<<8 | r<<4 | l[3:0]   -> qubits {7,6,5,4}
//  C: elem = r<<8  | w<<6  | l    r = elem[11:8] -> qubits {3,2,1,0}
// A and B share wave bits elem[11:10] -> the A->B transpose is INTRA-WAVE:
// LDS write + s_waitcnt lgkmcnt(0) + read, NO block barrier. Only B->C
// (wave bits move to elem[7:6]) needs one __syncthreads. Total barriers per
// row: 2 (tables + B->C) vs 9 in R10/R13 -> attacks the measured
// serialization (R13: HBM 41%, VALU 35%, both half-idle).
// All four LDS patterns hit the b64 minimum (4 lanes/bank-pair) under
// swz(idx) = idx ^ ((idx>>4)&15) applied to the local index.
template <bool INTERLEAVED>
__global__ __launch_bounds__(256, 4) void qlayer(
        const float* __restrict__ xr, const float* __restrict__ xi,
        const float* __restrict__ alphas, const float* __restrict__ betas,
        const float* __restrict__ thetas, const float* __restrict__ phis,
        float* __restrict__ out) {
    __shared__ float2 lds[DIM];
    __shared__ float2 mt[NQ][4];

    const int t = threadIdx.x;
    const int row = blockIdx.x;
    const int w = t >> 6, l = t & 63;
    const int abase = (w << 10) | (l << 4);   // 16 consecutive elems

    // ---- issue x loads immediately (layout A: 4x fv4, non-temporal) ----
    fv4 lre[4], lim[4];
    {
        const float* xrp = xr + (size_t)row * DIM + abase;
        const float* xip = xi + (size_t)row * DIM + abase;
#pragma unroll
        for (int c = 0; c < 4; ++c) {
            lre[c] = NT_LOAD(reinterpret_cast<const fv4*>(xrp + 4 * c));
            lim[c] = NT_LOAD(reinterpret_cast<const fv4*>(xip + 4 * c));
        }
    }

    // ---- 12 merged per-qubit 2x2 matrices (overlaps with x loads) ----
    if (t < NQ) {
        float sa, ca;
        sincosf(thetas[t], &sa, &ca);
        const float2 h0 = make_float2((ca - 1.f) * 0.5f, sa * 0.5f);   // (a-1)/2
        const float2 h1 = make_float2(-sa * 0.5f, (ca + 1.f) * 0.5f);  // i(a+1)/2
        const float al = alphas[t], be = betas[t], ph = phis[t];
        float s, c;
        sincosf(al + ph, &s, &c); mt[t][0] = cmulf(make_float2(c, s), h0);
        sincosf(al, &s, &c);      mt[t][1] = cmulf(make_float2(c, s), h1);
        sincosf(be + ph, &s, &c); mt[t][2] = cmulf(make_float2(c, s), h1);
        sincosf(be, &s, &c);      mt[t][3] = cmulf(make_float2(c, s),
                                                   make_float2(-h0.x, -h0.y));
    }
    __syncthreads();

    float vr[16], vi[16];
#pragma unroll
    for (int c = 0; c < 4; ++c)
#pragma unroll
        for (int j = 0; j < 4; ++j) {
            vr[c * 4 + j] = lre[c][j];
            vi[c * 4 + j] = lim[c][j];
        }

    apply4(vr, vi, mt, 11, 10, 9, 8);      // layout A: elem bits 0..3

    // ---- A -> B transpose: INTRA-WAVE (wave's private 1024-elem region) ----
    const int wbase = w << 10;
#pragma unroll
    for (int r = 0; r < 16; ++r) {
        // idx10 = l<<4 | r; swz -> l<<4 | (r ^ (l&15))
        const int s = wbase | (l << 4) | (r ^ (l & 15));
        lds[s] = make_float2(vr[r], vi[r]);
    }
    asm volatile("s_waitcnt lgkmcnt(0)" ::: "memory");
#pragma unroll
    for (int r = 0; r < 16; ++r) {
        // idx10 = l[5:4]<<8 | r<<4 | l[3:0]; swz -> ... | ((l&15) ^ r)
        const int s = wbase | ((l >> 4) << 8) | (r << 4) | ((l & 15) ^ r);
        const float2 v = lds[s];
        vr[r] = v.x; vi[r] = v.y;
    }

    apply4(vr, vi, mt, 7, 6, 5, 4);        // layout B: elem bits 4..7

    // ---- B -> C transpose: cross-wave, ONE block barrier ----
#pragma unroll
    for (int r = 0; r < 16; ++r) {
        // write back to the same (B-residency) slots we just read
        const int s = wbase | ((l >> 4) << 8) | (r << 4) | ((l & 15) ^ r);
        lds[s] = make_float2(vr[r], vi[r]);
    }
    __syncthreads();
#pragma unroll
    for (int r = 0; r < 16; ++r) {
        // e = r<<8 | w<<6 | l; swz low4: l[3:0] ^ (e[7:4] = w<<2 | l[5:4])
        const int s = (r << 8) | (w << 6) | (l & 48) |
                      ((l & 15) ^ ((w << 2) | (l >> 4)));
        const float2 v = lds[s];
        vr[r] = v.x; vi[r] = v.y;
    }

    apply4(vr, vi, mt, 3, 2, 1, 0);        // layout C: elem bits 8..11 — done

    // ---- store (layout C: e = r<<8 | w<<6 | l; 256B/512B per wave-instr) ----
    if (INTERLEAVED) {
        float2* outp = reinterpret_cast<float2*>(out) + (size_t)row * DIM;
#pragma unroll
        for (int r = 0; r < 16; ++r) {
            const int e = (r << 8) | (w << 6) | l;
            fv2 o; o.x = vr[r]; o.y = vi[r];
            NT_STORE(reinterpret_cast<fv2*>(outp + e), o);
        }
    } else {
        // Real part only: out is [BATCH][DIM] float32.
        float* outp = out + (size_t)row * DIM;
#pragma unroll
        for (int r = 0; r < 16; ++r) {
            const int e = (r << 8) | (w << 6) | l;
            NT_STORE(outp + e, vr[r]);
        }
    }
}

extern "C" void kernel_launch(void* const* d_in, const int* in_sizes, int n_in,
                              void* d_out, int out_size, void* d_ws, size_t ws_size,
                              hipStream_t stream) {
    const float* xr     = (const float*)d_in[0];
    const float* xi     = (const float*)d_in[1];
    const float* alphas = (const float*)d_in[2];
    const float* betas  = (const float*)d_in[3];
    const float* thetas = (const float*)d_in[4];
    const float* phis   = (const float*)d_in[5];

    // out_size-adaptive store: complex64 interleaved needs 2*BATCH*DIM floats;
    // the observed harness reference is BATCH*DIM float32 (real part).
    if (out_size >= 2 * BATCH * DIM) {
        qlayer<true><<<BATCH, 256, 0, stream>>>(xr, xi, alphas, betas, thetas,
                                                phis, (float*)d_out);
    } else {
        qlayer<false><<<BATCH, 256, 0, stream>>>(xr, xi, alphas, betas, thetas,
                                                 phis, (float*)d_out);
    }
}

// Round 16
// 122.146 us; speedup vs baseline: 1.3176x; 1.0468x over previous
//
#include <hip/hip_runtime.h>
#include <math.h>

#define NQ 12
#define DIM 4096
#define BATCH 2048

// Native clang vector types: __builtin_nontemporal_* requires true vectors of
// scalars, not HIP's HIP_vector_type classes.
typedef float fv4 __attribute__((ext_vector_type(4)));
typedef float fv2 __attribute__((ext_vector_type(2)));

#if defined(__has_builtin)
#if __has_builtin(__builtin_nontemporal_load) && __has_builtin(__builtin_nontemporal_store)
#define NT_LOAD(p)     __builtin_nontemporal_load(p)
#define NT_STORE(p, v) __builtin_nontemporal_store((v), (p))
#endif
#endif
#ifndef NT_LOAD
#define NT_LOAD(p)     (*(p))
#define NT_STORE(p, v) (*(p) = (v))
#endif

// Swizzle: XOR low-4 index bits with bits [7:4]. Re-derived for all six LDS
// access patterns below: every wave64 op lands at the b64 minimum
// (4 lanes per bank-pair).
__device__ __forceinline__ int swz(int e) { return e ^ ((e >> 4) & 15); }

__device__ __forceinline__ float2 cmulf(float2 a, float2 b) {
    return make_float2(a.x * b.x - a.y * b.y, a.x * b.y + a.y * b.x);
}

// One merged per-qubit 2x2 over thread-local bit m (row-vector convention):
//   (u', w') = (u*m00 + w*m10, u*m01 + w*m11)
// Matrices loaded per-stage (8 VGPR burst) to keep peak VGPR < 64 for
// 8 waves/SIMD.
__device__ __forceinline__ void applyq(float (&vr)[8], float (&vi)[8],
                                       const float2 (*mt)[4], int q, int m) {
    const float2 m00 = mt[q][0], m01 = mt[q][1], m10 = mt[q][2], m11 = mt[q][3];
#pragma unroll
    for (int r = 0; r < 8; ++r) {
        if (r & m) continue;
        const int p = r | m;
        const float ur = vr[r], ui = vi[r], wr = vr[p], wi = vi[p];
        vr[r] = fmaf(ur, m00.x, fmaf(-ui, m00.y, fmaf(wr, m10.x, -wi * m10.y)));
        vi[r] = fmaf(ur, m00.y, fmaf( ui, m00.x, fmaf(wr, m10.y,  wi * m10.x)));
        vr[p] = fmaf(ur, m01.x, fmaf(-ui, m01.y, fmaf(wr, m11.x, -wi * m11.y)));
        vi[p] = fmaf(ur, m01.y, fmaf( ui, m01.x, fmaf(wr, m11.y,  wi * m11.x)));
    }
}

__device__ __forceinline__ void apply3(float (&vr)[8], float (&vi)[8],
                                       const float2 (*mt)[4],
                                       int q1, int q2, int q4) {
    applyq(vr, vi, mt, q1, 1);
    applyq(vr, vi, mt, q2, 2);
    applyq(vr, vi, mt, q4, 4);
}

// Whole op per qubit k is ONE 2x2 (row-vector x @ M), HW-verified (R14/R15
// pass with identical absmax to the 3-diagonal form):
//   a = e^{i theta}:
//   M00 = e^{i(alpha+phi)} (a-1)/2        M01 = e^{i alpha} i(a+1)/2
//   M10 = e^{i(beta+phi)}  i(a+1)/2       M11 = e^{i beta}  (1-a)/2
//
// 512 threads/block (t = w<<6|l, w = t[8:6], l = t[5:0]), 8 elems/thread,
// 4 phases x 3 qubits (qubit k <-> elem bit 11-k):
//  A: elem = t<<3 | r                 r = elem[2:0]  -> qubits {11,10,9}
//  B: elem = t[8:3]<<6 | r<<3 | t[2:0]  r = elem[5:3] -> qubits {8,7,6}
//  C: elem = w<<9 | r<<6 | l          r = elem[8:6]  -> qubits {5,4,3}
//  D: elem = r<<9 | t                 r = elem[11:9] -> qubits {2,1,0}
// A,B,C all keep wave bits = elem[11:9] -> A->B and B->C are INTRA-WAVE
// (ds write + lgkmcnt(0) + read, no barrier; regions disjoint per wave).
// Only C->D needs one __syncthreads. 2 barriers/block total.
// R15 PMC: VALU 35%, HBM 16%, 50% static occupancy -> stall-bound. This
// doubles occupancy (32 waves/CU) and halves per-thread instr count.
template <bool INTERLEAVED>
__global__ __launch_bounds__(512, 8) void qlayer(
        const float* __restrict__ xr, const float* __restrict__ xi,
        const float* __restrict__ alphas, const float* __restrict__ betas,
        const float* __restrict__ thetas, const float* __restrict__ phis,
        float* __restrict__ out) {
    __shared__ float2 lds[DIM];
    __shared__ float2 mt[NQ][4];

    const int t = threadIdx.x;           // 0..511
    const int row = blockIdx.x;
    const int w = t >> 6, l = t & 63;

    // ---- issue x loads immediately (8 consecutive elems, 2x fv4 each) ----
    fv4 lre[2], lim[2];
    {
        const float* xrp = xr + (size_t)row * DIM + (t << 3);
        const float* xip = xi + (size_t)row * DIM + (t << 3);
        lre[0] = NT_LOAD(reinterpret_cast<const fv4*>(xrp));
        lre[1] = NT_LOAD(reinterpret_cast<const fv4*>(xrp + 4));
        lim[0] = NT_LOAD(reinterpret_cast<const fv4*>(xip));
        lim[1] = NT_LOAD(reinterpret_cast<const fv4*>(xip + 4));
    }

    // ---- 12 merged per-qubit 2x2 matrices (overlaps with x loads) ----
    if (t < NQ) {
        float sa, ca;
        sincosf(thetas[t], &sa, &ca);
        const float2 h0 = make_float2((ca - 1.f) * 0.5f, sa * 0.5f);   // (a-1)/2
        const float2 h1 = make_float2(-sa * 0.5f, (ca + 1.f) * 0.5f);  // i(a+1)/2
        const float al = alphas[t], be = betas[t], ph = phis[t];
        float s, c;
        sincosf(al + ph, &s, &c); mt[t][0] = cmulf(make_float2(c, s), h0);
        sincosf(al, &s, &c);      mt[t][1] = cmulf(make_float2(c, s), h1);
        sincosf(be + ph, &s, &c); mt[t][2] = cmulf(make_float2(c, s), h1);
        sincosf(be, &s, &c);      mt[t][3] = cmulf(make_float2(c, s),
                                                   make_float2(-h0.x, -h0.y));
    }
    __syncthreads();

    float vr[8], vi[8];
#pragma unroll
    for (int j = 0; j < 4; ++j) {
        vr[j] = lre[0][j];     vi[j] = lim[0][j];
        vr[4 + j] = lre[1][j]; vi[4 + j] = lim[1][j];
    }

    apply3(vr, vi, mt, 11, 10, 9);       // layout A: elem bits 0..2

    // ---- A -> B transpose: INTRA-WAVE (wave region elem[11:9] = w) ----
#pragma unroll
    for (int r = 0; r < 8; ++r)
        lds[swz((t << 3) | r)] = make_float2(vr[r], vi[r]);
    asm volatile("s_waitcnt lgkmcnt(0)" ::: "memory");
#pragma unroll
    for (int r = 0; r < 8; ++r) {
        const float2 v = lds[swz(((t >> 3) << 6) | (r << 3) | (t & 7))];
        vr[r] = v.x; vi[r] = v.y;
    }

    apply3(vr, vi, mt, 8, 7, 6);         // layout B: elem bits 3..5

    // ---- B -> C transpose: INTRA-WAVE (same-wave DS ops are in-order,
    //      so WAR on the just-read addresses is safe) ----
#pragma unroll
    for (int r = 0; r < 8; ++r)
        lds[swz(((t >> 3) << 6) | (r << 3) | (t & 7))] =
            make_float2(vr[r], vi[r]);
    asm volatile("s_waitcnt lgkmcnt(0)" ::: "memory");
#pragma unroll
    for (int r = 0; r < 8; ++r) {
        const float2 v = lds[swz((w << 9) | (r << 6) | l)];
        vr[r] = v.x; vi[r] = v.y;
    }

    apply3(vr, vi, mt, 5, 4, 3);         // layout C: elem bits 6..8

    // ---- C -> D transpose: cross-wave, the ONE block barrier ----
#pragma unroll
    for (int r = 0; r < 8; ++r)
        lds[swz((w << 9) | (r << 6) | l)] = make_float2(vr[r], vi[r]);
    __syncthreads();
#pragma unroll
    for (int r = 0; r < 8; ++r) {
        const float2 v = lds[swz((r << 9) | t)];
        vr[r] = v.x; vi[r] = v.y;
    }

    apply3(vr, vi, mt, 2, 1, 0);         // layout D: elem bits 9..11 — done

    // ---- store (layout D: e = r<<9 | t; 256B/512B per wave-instr) ----
    if (INTERLEAVED) {
        float2* outp = reinterpret_cast<float2*>(out) + (size_t)row * DIM;
#pragma unroll
        for (int r = 0; r < 8; ++r) {
            const int e = (r << 9) | t;
            fv2 o; o.x = vr[r]; o.y = vi[r];
            NT_STORE(reinterpret_cast<fv2*>(outp + e), o);
        }
    } else {
        // Real part only: out is [BATCH][DIM] float32.
        float* outp = out + (size_t)row * DIM;
#pragma unroll
        for (int r = 0; r < 8; ++r) {
            const int e = (r << 9) | t;
            NT_STORE(outp + e, vr[r]);
        }
    }
}

extern "C" void kernel_launch(void* const* d_in, const int* in_sizes, int n_in,
                              void* d_out, int out_size, void* d_ws, size_t ws_size,
                              hipStream_t stream) {
    const float* xr     = (const float*)d_in[0];
    const float* xi     = (const float*)d_in[1];
    const float* alphas = (const float*)d_in[2];
    const float* betas  = (const float*)d_in[3];
    const float* thetas = (const float*)d_in[4];
    const float* phis   = (const float*)d_in[5];

    // out_size-adaptive store: complex64 interleaved needs 2*BATCH*DIM floats;
    // the observed harness reference is BATCH*DIM float32 (real part).
    if (out_size >= 2 * BATCH * DIM) {
        qlayer<true><<<BATCH, 512, 0, stream>>>(xr, xi, alphas, betas, thetas,
                                                phis, (float*)d_out);
    } else {
        qlayer<false><<<BATCH, 512, 0, stream>>>(xr, xi, alphas, betas, thetas,
                                                 phis, (float*)d_out);
    }
}